// Round 2
// baseline (534.543 us; speedup 1.0000x reference)
//
#include <hip/hip_runtime.h>

#define TPB 256

// ---------------------------------------------------------------------------
// ws layout: ws[0..B-1] = per-cloud max of ||xyz|| (float, >= 0)
// ---------------------------------------------------------------------------

__global__ void init_ws_kernel(float* ws, int b) {
    int t = blockIdx.x * blockDim.x + threadIdx.x;
    if (t < b) ws[t] = 0.0f;
}

// Per-cloud max global distance. Wave-uniform fast path: one atomic per wave.
__global__ __launch_bounds__(TPB) void seg_max_kernel(
    const float* __restrict__ xyz,
    const int* __restrict__ lengths,
    float* __restrict__ segmax,
    int n, int b)
{
    int i = blockIdx.x * blockDim.x + threadIdx.x;
    float d = 0.0f;
    int s = 0;
    if (i < n) {
        float x = xyz[3 * i], y = xyz[3 * i + 1], z = xyz[3 * i + 2];
        d = sqrtf(x * x + y * y + z * z);
        int c = 0;
        s = b - 1;
        for (int j = 0; j < b; ++j) {
            c += lengths[j];
            if (i < c) { s = j; break; }
        }
    }
    // fast path: whole 64-lane wave in same segment (true except at boundaries)
    int s0 = __shfl(s, 0);
    if (__all(s == s0)) {
        for (int off = 32; off; off >>= 1)
            d = fmaxf(d, __shfl_xor(d, off));
        if ((threadIdx.x & 63) == 0 && d > 0.0f)
            atomicMax((int*)&segmax[s0], __float_as_int(d));  // d>=0: int order == float order
    } else {
        if (i < n)
            atomicMax((int*)&segmax[s], __float_as_int(d));
    }
}

// ---------------------------------------------------------------------------
// Main kernel: K=16 threads per point. Thread (i,k) handles neighbor k of
// point i. 16-lane shfl reductions for centroid mean + max distance.
// local_rep staged in LDS and written back as coalesced float4s.
// ---------------------------------------------------------------------------
__global__ __launch_bounds__(TPB) void lpr_main_kernel(
    const float* __restrict__ xyz,
    const int* __restrict__ neigh,
    const int* __restrict__ lengths,
    const float* __restrict__ segmax,
    float* __restrict__ out_rep,   // [N,K,9]
    float* __restrict__ out_gd,    // [N,K]
    float* __restrict__ out_lg,    // [N]
    int n, int b)
{
    __shared__ __align__(16) float srep[TPB * 9];

    const int t = threadIdx.x;
    const int g = blockIdx.x * TPB + t;   // global (i,k) index
    const int i = g >> 4;                 // K = 16
    const int k = g & 15;
    const bool active = (i < n);

    float px = 0.f, py = 0.f, pz = 0.f;
    float nx = 0.f, ny = 0.f, nz = 0.f;
    if (active) {
        px = xyz[3 * i];
        py = xyz[3 * i + 1];
        pz = xyz[3 * i + 2];
        int idx = neigh[g];
        if ((unsigned)idx < (unsigned)n) {   // index n == zero pad row
            nx = xyz[3 * idx];
            ny = xyz[3 * idx + 1];
            nz = xyz[3 * idx + 2];
        }
    }

    const float rx = px - nx, ry = py - ny, rz = pz - nz;
    const float ralpha = atan2f(ry, rx);
    const float rxy    = sqrtf(rx * rx + ry * ry);
    const float rbeta  = atan2f(rz, rxy);
    const float rdis   = sqrtf(rx * rx + ry * ry + rz * rz);

    // 16-lane reductions: neighbor centroid sum + max distance
    float sx = nx, sy = ny, sz = nz, md = rdis;
    for (int off = 8; off; off >>= 1) {
        sx += __shfl_xor(sx, off, 16);
        sy += __shfl_xor(sy, off, 16);
        sz += __shfl_xor(sz, off, 16);
        md = fmaxf(md, __shfl_xor(md, off, 16));
    }

    const float dx = px - sx * 0.0625f;   // 1/16
    const float dy = py - sy * 0.0625f;
    const float dz = pz - sz * 0.0625f;
    const float dalpha = atan2f(dy, dx);
    const float dbeta  = atan2f(dz, sqrtf(dx * dx + dy * dy));

    // stage 9-wide rep row in LDS (stride 9 floats = odd -> bank-conflict-free)
    float* s9 = &srep[t * 9];
    s9[0] = ralpha - dalpha;
    s9[1] = rbeta - dbeta;
    s9[2] = rdis;
    s9[3] = px; s9[4] = py; s9[5] = pz;
    s9[6] = nx; s9[7] = ny; s9[8] = nz;

    // geometric_dis: perfectly coalesced scalar store
    if (active) out_gd[g] = expf(-rdis);

    // lg_volume_ratio: one lane per point
    if (active && k == 0) {
        int s = b - 1, c = 0;
        for (int j = 0; j < b; ++j) {
            c += lengths[j];
            if (i < c) { s = j; break; }
        }
        const float gv = segmax[s];
        out_lg[i] = (md * md * md) / gv;
    }

    __syncthreads();

    // cooperative coalesced write of this block's [TPB*9] floats
    const long long base = (long long)blockIdx.x * (TPB * 9);
    const long long limit = (long long)n * 16 * 9;
    if (base + TPB * 9 <= limit) {
        float4* dst = (float4*)(out_rep + base);
        const float4* src = (const float4*)srep;
        #pragma unroll
        for (int j = t; j < TPB * 9 / 4; j += TPB)
            dst[j] = src[j];
    } else {
        // partial tail block (not hit for N=524288): scalar guarded writes
        for (int j = t; j < TPB * 9; j += TPB)
            if (base + j < limit) out_rep[base + j] = srep[j];
    }
}

// ---------------------------------------------------------------------------

extern "C" void kernel_launch(void* const* d_in, const int* in_sizes, int n_in,
                              void* d_out, int out_size, void* d_ws, size_t ws_size,
                              hipStream_t stream) {
    const float* xyz     = (const float*)d_in[0];
    const int*   neigh   = (const int*)d_in[1];
    const int*   lengths = (const int*)d_in[2];

    const int n = in_sizes[0] / 3;       // 524288
    const int b = in_sizes[2];           // 8
    // K is fixed at 16 by the reference (kernel hard-codes the 16-lane groups)

    float* segmax = (float*)d_ws;
    float* out      = (float*)d_out;
    float* out_rep  = out;                                // N*K*9
    float* out_gd   = out + (long long)n * 16 * 9;        // N*K
    float* out_lg   = out_gd + (long long)n * 16;         // N

    init_ws_kernel<<<1, 256, 0, stream>>>(segmax, b);

    const int blocks1 = (n + TPB - 1) / TPB;
    seg_max_kernel<<<blocks1, TPB, 0, stream>>>(xyz, lengths, segmax, n, b);

    const long long total = (long long)n * 16;
    const int blocks2 = (int)((total + TPB - 1) / TPB);
    lpr_main_kernel<<<blocks2, TPB, 0, stream>>>(xyz, neigh, lengths, segmax,
                                                 out_rep, out_gd, out_lg, n, b);
}

// Round 5
// 511.918 us; speedup vs baseline: 1.0442x; 1.0442x over previous
//
#include <hip/hip_runtime.h>

#define TPB 256

typedef float floatx4 __attribute__((ext_vector_type(4)));  // builtin-compatible

// ---------------------------------------------------------------------------
// Fast transcendentals (errors ~2e-6, vs harness-tolerated absmax 0.125)
// ---------------------------------------------------------------------------

// Branch-cut-correct atan2: quadrant logic identical to IEEE atan2.
// atan2(0,0) -> 0 (matches jnp.arctan2). Sign of y restored via copysignf.
__device__ __forceinline__ float fast_atan2f(float y, float x) {
    float ax = __builtin_fabsf(x), ay = __builtin_fabsf(y);
    float mx = fmaxf(ax, ay), mn = fminf(ax, ay);
    float t  = mn * __builtin_amdgcn_rcpf(mx);   // mn/mx in [0,1]
    if (mx == 0.0f) t = 0.0f;                    // (0,0): avoid 0*inf=NaN
    float t2 = t * t;
    // minimax odd poly for atan(t), t in [0,1], max err ~2e-6
    float p = fmaf(t2, -0.01172120f, 0.05265332f);
    p = fmaf(t2, p, -0.11643287f);
    p = fmaf(t2, p,  0.19354346f);
    p = fmaf(t2, p, -0.33262347f);
    p = fmaf(t2, p,  0.99997726f);
    float r = t * p;
    if (ay > ax)   r = 1.5707963267948966f - r;  // reflect past 45 deg
    if (x < 0.0f)  r = 3.1415926535897931f - r;  // left half-plane
    return copysignf(r, y);
}

__device__ __forceinline__ float fast_sqrtf(float x) {
    return __builtin_amdgcn_sqrtf(x);            // v_sqrt_f32, ~1 ulp
}

__device__ __forceinline__ float fast_expf(float x) {
    return __builtin_amdgcn_exp2f(x * 1.4426950408889634f);  // v_exp_f32
}

// ---------------------------------------------------------------------------
// ws layout: ws[0..B-1] = per-cloud max of ||xyz|| (float, >= 0)
// ---------------------------------------------------------------------------

__global__ void init_ws_kernel(float* ws, int b) {
    int t = blockIdx.x * blockDim.x + threadIdx.x;
    if (t < b) ws[t] = 0.0f;
}

// Per-cloud max global distance. Segment boundaries (65536) are block-aligned,
// so every wave is segment-uniform -> one atomic per wave.
__global__ __launch_bounds__(TPB) void seg_max_kernel(
    const float* __restrict__ xyz,
    const int* __restrict__ lengths,
    float* __restrict__ segmax,
    int n, int b)
{
    int i = blockIdx.x * blockDim.x + threadIdx.x;
    float d = 0.0f;
    int s = 0;
    if (i < n) {
        float x = xyz[3 * i], y = xyz[3 * i + 1], z = xyz[3 * i + 2];
        d = fast_sqrtf(x * x + y * y + z * z);
        int c = 0;
        s = b - 1;
        for (int j = 0; j < b; ++j) {
            c += lengths[j];
            if (i < c) { s = j; break; }
        }
    }
    int s0 = __shfl(s, 0);
    if (__all(s == s0)) {
        for (int off = 32; off; off >>= 1)
            d = fmaxf(d, __shfl_xor(d, off));
        if ((threadIdx.x & 63) == 0 && d > 0.0f)
            atomicMax((int*)&segmax[s0], __float_as_int(d));  // d>=0: int order == float order
    } else {
        if (i < n)
            atomicMax((int*)&segmax[s], __float_as_int(d));
    }
}

// ---------------------------------------------------------------------------
// Main kernel: K=16 threads per point. 16-lane shfl reductions for centroid
// mean + max distance. local_rep staged in LDS, written back as coalesced
// NON-TEMPORAL 16B stores (302 MB stream must not evict the 6.3 MB xyz
// gather working set from L2).
// ---------------------------------------------------------------------------
__global__ __launch_bounds__(TPB) void lpr_main_kernel(
    const float* __restrict__ xyz,
    const int* __restrict__ neigh,
    const int* __restrict__ lengths,
    const float* __restrict__ segmax,
    float* __restrict__ out_rep,   // [N,K,9]
    float* __restrict__ out_gd,    // [N,K]
    float* __restrict__ out_lg,    // [N]
    int n, int b)
{
    __shared__ __align__(16) float srep[TPB * 9];

    const int t = threadIdx.x;
    const int g = blockIdx.x * TPB + t;   // global (i,k) index
    const int i = g >> 4;                 // K = 16
    const int k = g & 15;
    const bool active = (i < n);

    float px = 0.f, py = 0.f, pz = 0.f;
    float nx = 0.f, ny = 0.f, nz = 0.f;
    if (active) {
        px = xyz[3 * i];
        py = xyz[3 * i + 1];
        pz = xyz[3 * i + 2];
        int idx = __builtin_nontemporal_load(&neigh[g]);  // streamed, no reuse
        if ((unsigned)idx < (unsigned)n) {   // index n == zero pad row
            nx = xyz[3 * idx];
            ny = xyz[3 * idx + 1];
            nz = xyz[3 * idx + 2];
        }
    }

    const float rx = px - nx, ry = py - ny, rz = pz - nz;
    const float ralpha = fast_atan2f(ry, rx);
    const float rxy    = fast_sqrtf(rx * rx + ry * ry);
    const float rbeta  = fast_atan2f(rz, rxy);
    const float rdis   = fast_sqrtf(rx * rx + ry * ry + rz * rz);

    // 16-lane reductions: neighbor centroid sum + max distance
    float sx = nx, sy = ny, sz = nz, md = rdis;
    for (int off = 8; off; off >>= 1) {
        sx += __shfl_xor(sx, off, 16);
        sy += __shfl_xor(sy, off, 16);
        sz += __shfl_xor(sz, off, 16);
        md = fmaxf(md, __shfl_xor(md, off, 16));
    }

    const float dx = px - sx * 0.0625f;   // 1/16
    const float dy = py - sy * 0.0625f;
    const float dz = pz - sz * 0.0625f;
    const float dalpha = fast_atan2f(dy, dx);
    const float dbeta  = fast_atan2f(dz, fast_sqrtf(dx * dx + dy * dy));

    // stage 9-wide rep row in LDS (stride 9 floats = odd -> <=2 lanes/bank, free)
    float* s9 = &srep[t * 9];
    s9[0] = ralpha - dalpha;
    s9[1] = rbeta - dbeta;
    s9[2] = rdis;
    s9[3] = px; s9[4] = py; s9[5] = pz;
    s9[6] = nx; s9[7] = ny; s9[8] = nz;

    // geometric_dis: coalesced non-temporal store
    if (active) __builtin_nontemporal_store(fast_expf(-rdis), &out_gd[g]);

    // lg_volume_ratio: one lane per point
    if (active && k == 0) {
        int s = b - 1, c = 0;
        for (int j = 0; j < b; ++j) {
            c += lengths[j];
            if (i < c) { s = j; break; }
        }
        const float gv = segmax[s];
        out_lg[i] = (md * md * md) / gv;
    }

    __syncthreads();

    // cooperative coalesced write of this block's [TPB*9] floats, non-temporal
    const long long base = (long long)blockIdx.x * (TPB * 9);
    const long long limit = (long long)n * 16 * 9;
    if (base + TPB * 9 <= limit) {
        floatx4* dst = (floatx4*)(out_rep + base);
        const floatx4* src = (const floatx4*)srep;
        for (int j = t; j < TPB * 9 / 4; j += TPB)
            __builtin_nontemporal_store(src[j], &dst[j]);
    } else {
        // partial tail block (not hit for N=524288): scalar guarded writes
        for (int j = t; j < TPB * 9; j += TPB)
            if (base + j < limit) out_rep[base + j] = srep[j];
    }
}

// ---------------------------------------------------------------------------

extern "C" void kernel_launch(void* const* d_in, const int* in_sizes, int n_in,
                              void* d_out, int out_size, void* d_ws, size_t ws_size,
                              hipStream_t stream) {
    const float* xyz     = (const float*)d_in[0];
    const int*   neigh   = (const int*)d_in[1];
    const int*   lengths = (const int*)d_in[2];

    const int n = in_sizes[0] / 3;       // 524288
    const int b = in_sizes[2];           // 8

    float* segmax = (float*)d_ws;
    float* out      = (float*)d_out;
    float* out_rep  = out;                                // N*K*9
    float* out_gd   = out + (long long)n * 16 * 9;        // N*K
    float* out_lg   = out_gd + (long long)n * 16;         // N

    init_ws_kernel<<<1, 256, 0, stream>>>(segmax, b);

    const int blocks1 = (n + TPB - 1) / TPB;
    seg_max_kernel<<<blocks1, TPB, 0, stream>>>(xyz, lengths, segmax, n, b);

    const long long total = (long long)n * 16;
    const int blocks2 = (int)((total + TPB - 1) / TPB);
    lpr_main_kernel<<<blocks2, TPB, 0, stream>>>(xyz, neigh, lengths, segmax,
                                                 out_rep, out_gd, out_lg, n, b);
}